// Round 6
// baseline (197.645 us; speedup 1.0000x reference)
//
#include <hip/hip_runtime.h>
#include <math.h>

#define BB 64
#define NN 512
#define FF 128
#define PADT 129   // transpose buffer pad

typedef __bf16 bf16x8 __attribute__((ext_vector_type(8)));
typedef float floatx4 __attribute__((ext_vector_type(4)));

// round-to-nearest-even f32 -> bf16 bits
__device__ __forceinline__ unsigned int bf16u(float f) {
    unsigned int u = __builtin_bit_cast(unsigned int, f);
    unsigned int r = (u + 0x7FFFu + ((u >> 16) & 1u)) >> 16;
    return r & 0xFFFFu;
}

// ---- Kernel 1: fused row-softmax(w) -> S  AND  dvec[b,i] for 16 batches ----
__global__ __launch_bounds__(256) void softmax_rowsum_kernel(
        const float* __restrict__ w, const float* __restrict__ mask,
        float* __restrict__ S, float* __restrict__ dvec) {
    __shared__ float Srow[NN];
    __shared__ float red[8];
    const int row = blockIdx.x;
    const int bg = blockIdx.y;
    const int tid = threadIdx.x;
    const int wv = tid >> 6, lane = tid & 63;

    float v0 = w[(size_t)row * NN + tid];
    float v1 = w[(size_t)row * NN + tid + 256];

    float m = fmaxf(v0, v1);
    #pragma unroll
    for (int off = 32; off > 0; off >>= 1)
        m = fmaxf(m, __shfl_down(m, off, 64));
    if (lane == 0) red[wv] = m;
    __syncthreads();
    if (tid == 0) red[4] = fmaxf(fmaxf(red[0], red[1]), fmaxf(red[2], red[3]));
    __syncthreads();
    m = red[4];

    float e0 = expf(v0 - m);
    float e1 = expf(v1 - m);
    float s = e0 + e1;
    #pragma unroll
    for (int off = 32; off > 0; off >>= 1)
        s += __shfl_down(s, off, 64);
    __syncthreads();
    if (lane == 0) red[wv] = s;
    __syncthreads();
    if (tid == 0) red[5] = 1.0f / (red[0] + red[1] + red[2] + red[3]);
    __syncthreads();
    const float inv = red[5];
    const float s0v = e0 * inv, s1v = e1 * inv;

    Srow[tid] = s0v;
    Srow[tid + 256] = s1v;
    if (bg == 0) {
        S[(size_t)row * NN + tid] = s0v;
        S[(size_t)row * NN + tid + 256] = s1v;
    }
    __syncthreads();

    float4 sA = *(const float4*)&Srow[lane * 8];
    float4 sB = *(const float4*)&Srow[lane * 8 + 4];

    float4 mA[4], mB[4];
    #pragma unroll
    for (int t = 0; t < 4; ++t) {
        int b = bg * 16 + wv * 4 + t;
        const float4* mrow = (const float4*)(mask + ((size_t)b * NN + row) * NN);
        mA[t] = mrow[2 * lane];
        mB[t] = mrow[2 * lane + 1];
    }
    #pragma unroll
    for (int t = 0; t < 4; ++t) {
        float sum = mA[t].x * sA.x + mA[t].y * sA.y + mA[t].z * sA.z + mA[t].w * sA.w
                  + mB[t].x * sB.x + mB[t].y * sB.y + mB[t].z * sB.z + mB[t].w * sB.w;
        #pragma unroll
        for (int off = 32; off > 0; off >>= 1)
            sum += __shfl_down(sum, off, 64);
        if (lane == 0) {
            int b = bg * 16 + wv * 4 + t;
            float rs = sum + 1.0f;
            dvec[b * NN + row] = (rs > 0.f) ? (1.0f / sqrtf(rs)) : 0.f;
        }
    }
}

// ---- Kernel 2: Xt[b][f][j] = bf16(d_j * x[b][j][f])  (per-batch transpose) -
__global__ __launch_bounds__(256) void xt_kernel(const float* __restrict__ in,
                                                 const float* __restrict__ dvec,
                                                 unsigned short* __restrict__ Xt) {
    __shared__ unsigned short T[64 * PADT];
    const int b = blockIdx.y;
    const int j0 = blockIdx.x * 64;
    const int tid = threadIdx.x;

    const int fg = tid & 31;
    const int jr = tid >> 5;
    #pragma unroll
    for (int p = 0; p < 8; ++p) {
        int j = jr + 8 * p;
        float dj = dvec[b * NN + j0 + j];
        float4 xv = *(const float4*)(in + ((size_t)b * NN + j0 + j) * FF + 4 * fg);
        T[j * PADT + 4 * fg + 0] = (unsigned short)bf16u(xv.x * dj);
        T[j * PADT + 4 * fg + 1] = (unsigned short)bf16u(xv.y * dj);
        T[j * PADT + 4 * fg + 2] = (unsigned short)bf16u(xv.z * dj);
        T[j * PADT + 4 * fg + 3] = (unsigned short)bf16u(xv.w * dj);
    }
    __syncthreads();
    const int c = tid & 7;
    const int fr = tid >> 3;
    #pragma unroll
    for (int q = 0; q < 4; ++q) {
        int f = fr + 32 * q;
        unsigned int v01 = (unsigned int)T[(8 * c + 0) * PADT + f] |
                           ((unsigned int)T[(8 * c + 1) * PADT + f] << 16);
        unsigned int v23 = (unsigned int)T[(8 * c + 2) * PADT + f] |
                           ((unsigned int)T[(8 * c + 3) * PADT + f] << 16);
        unsigned int v45 = (unsigned int)T[(8 * c + 4) * PADT + f] |
                           ((unsigned int)T[(8 * c + 5) * PADT + f] << 16);
        unsigned int v67 = (unsigned int)T[(8 * c + 6) * PADT + f] |
                           ((unsigned int)T[(8 * c + 7) * PADT + f] << 16);
        *(uint4*)(Xt + ((size_t)b * FF + f) * NN + j0 + 8 * c) = make_uint4(v01, v23, v45, v67);
    }
}

// ---- Kernel 3: MFMA matmul, NO LDS, NO barriers — pure streaming ----------
// block (i-tile 16 rows, batch b), 256 thr = 4 waves; wave wv covers f-slice
// fw=wv*32 (2 n-tiles). A-frags built in-register from global mask*S (the
// 64 MB stream); B-frags from L2-resident Xt. 16 k-steps, unroll 4 so the
// compiler hoists ~4 steps of loads (distance-4 prefetch).
__global__ __launch_bounds__(256) void matmul_kernel(
        const float* __restrict__ S, const float* __restrict__ mask,
        const float* __restrict__ dvec, const unsigned short* __restrict__ Xt,
        const float* __restrict__ in, float* __restrict__ out) {
    const int b = blockIdx.y;
    const int i_base = blockIdx.x * 16;
    const int tid = threadIdx.x;
    const int wv = tid >> 6;
    const int lane = tid & 63;
    const int q = lane >> 4;    // quad -> k offset q*8
    const int r = lane & 15;    // A row index / B f index
    const int fw = wv * 32;

    // per-lane base pointers (row r, k-offset q*8 baked in)
    const float* mrow = mask + ((size_t)b * NN + i_base + r) * NN + q * 8;
    const float* srow = S + (size_t)(i_base + r) * NN + q * 8;
    const unsigned short* xb0 = Xt + ((size_t)b * FF + fw + r) * NN + q * 8;
    const unsigned short* xb1 = xb0 + (size_t)16 * NN;

    floatx4 acc0 = (floatx4){0.f, 0.f, 0.f, 0.f};
    floatx4 acc1 = (floatx4){0.f, 0.f, 0.f, 0.f};

    #pragma unroll 4
    for (int s = 0; s < 16; ++s) {
        const int o = s * 32;
        float4 ma0 = *(const float4*)(mrow + o);
        float4 ma1 = *(const float4*)(mrow + o + 4);
        float4 sa0 = *(const float4*)(srow + o);
        float4 sa1 = *(const float4*)(srow + o + 4);
        bf16x8 b0 = *(const bf16x8*)(xb0 + o);
        bf16x8 b1 = *(const bf16x8*)(xb1 + o);

        bf16x8 af;
        af[0] = (__bf16)(ma0.x * sa0.x);
        af[1] = (__bf16)(ma0.y * sa0.y);
        af[2] = (__bf16)(ma0.z * sa0.z);
        af[3] = (__bf16)(ma0.w * sa0.w);
        af[4] = (__bf16)(ma1.x * sa1.x);
        af[5] = (__bf16)(ma1.y * sa1.y);
        af[6] = (__bf16)(ma1.z * sa1.z);
        af[7] = (__bf16)(ma1.w * sa1.w);

        acc0 = __builtin_amdgcn_mfma_f32_16x16x32_bf16(af, b0, acc0, 0, 0, 0);
        acc1 = __builtin_amdgcn_mfma_f32_16x16x32_bf16(af, b1, acc1, 0, 0, 0);
    }

    // epilogue: out = d_i * (acc + d_i * x_i); C/D layout col=r, row=q*4+reg
    const float* dB = dvec + b * NN;
    #pragma unroll
    for (int nt = 0; nt < 2; ++nt) {
        int f = fw + nt * 16 + r;
        const floatx4& a = nt ? acc1 : acc0;
        #pragma unroll
        for (int rr = 0; rr < 4; ++rr) {
            int i = i_base + q * 4 + rr;
            float di = dB[i];
            float x = in[((size_t)b * NN + i) * FF + f];
            out[((size_t)b * NN + i) * FF + f] = di * (a[rr] + di * x);
        }
    }
}

extern "C" void kernel_launch(void* const* d_in, const int* in_sizes, int n_in,
                              void* d_out, int out_size, void* d_ws, size_t ws_size,
                              hipStream_t stream) {
    const float* inp  = (const float*)d_in[0];   // [B,N,F]
    const float* mask = (const float*)d_in[1];   // [B,N,N]
    const float* w    = (const float*)d_in[2];   // [N,N]
    float* out = (float*)d_out;                  // [B,N,F]

    unsigned short* Xt = (unsigned short*)d_ws;              // B*F*N bf16 = 8 MB
    float* S    = (float*)(Xt + (size_t)BB * FF * NN);       // N*N f32 = 1 MB
    float* dvec = S + (size_t)NN * NN;                       // B*N f32

    softmax_rowsum_kernel<<<dim3(NN, 4), 256, 0, stream>>>(w, mask, S, dvec);
    xt_kernel<<<dim3(NN / 64, BB), 256, 0, stream>>>(inp, dvec, Xt);
    matmul_kernel<<<dim3(NN / 16, BB), 256, 0, stream>>>(S, mask, dvec, Xt, inp, out);
}

// Round 7
// 153.007 us; speedup vs baseline: 1.2917x; 1.2917x over previous
//
#include <hip/hip_runtime.h>
#include <math.h>

#define BB 64
#define NN 512
#define FF 128
#define ASTR 72    // bf16 elems per A-row in LDS (144 B rows, 16B-aligned)
#define PADT 129   // transpose buffer pad
#define TI2 16     // matmul i-tile

typedef __bf16 bf16x8 __attribute__((ext_vector_type(8)));
typedef float floatx4 __attribute__((ext_vector_type(4)));

// round-to-nearest-even f32 -> bf16 bits
__device__ __forceinline__ unsigned int bf16u(float f) {
    unsigned int u = __builtin_bit_cast(unsigned int, f);
    unsigned int r = (u + 0x7FFFu + ((u >> 16) & 1u)) >> 16;
    return r & 0xFFFFu;
}

// ---- Kernel 1: row-softmax(w) (in-block) -> A[b]=bf16(S*mask) + dvec -------
// grid (NN, 4): block = (row i, batch-group bg of 16 batches). Each wave
// handles 4 batches: writes A[b][row][:] bf16 and dvec[b,row].
__global__ __launch_bounds__(256) void softmax_rowsum_A_kernel(
        const float* __restrict__ w, const float* __restrict__ mask,
        unsigned short* __restrict__ A, float* __restrict__ dvec) {
    __shared__ float Srow[NN];
    __shared__ float red[8];
    const int row = blockIdx.x;
    const int bg = blockIdx.y;
    const int tid = threadIdx.x;
    const int wv = tid >> 6, lane = tid & 63;

    float v0 = w[(size_t)row * NN + tid];
    float v1 = w[(size_t)row * NN + tid + 256];

    float m = fmaxf(v0, v1);
    #pragma unroll
    for (int off = 32; off > 0; off >>= 1)
        m = fmaxf(m, __shfl_down(m, off, 64));
    if (lane == 0) red[wv] = m;
    __syncthreads();
    if (tid == 0) red[4] = fmaxf(fmaxf(red[0], red[1]), fmaxf(red[2], red[3]));
    __syncthreads();
    m = red[4];

    float e0 = expf(v0 - m);
    float e1 = expf(v1 - m);
    float s = e0 + e1;
    #pragma unroll
    for (int off = 32; off > 0; off >>= 1)
        s += __shfl_down(s, off, 64);
    __syncthreads();
    if (lane == 0) red[wv] = s;
    __syncthreads();
    if (tid == 0) red[5] = 1.0f / (red[0] + red[1] + red[2] + red[3]);
    __syncthreads();
    const float inv = red[5];

    Srow[tid] = e0 * inv;
    Srow[tid + 256] = e1 * inv;
    __syncthreads();

    // lane covers j = lane*8 .. lane*8+7
    float4 sA = *(const float4*)&Srow[lane * 8];
    float4 sB = *(const float4*)&Srow[lane * 8 + 4];

    // 4 batches per wave; all mask loads issued first (16 in flight)
    float4 mA[4], mB[4];
    #pragma unroll
    for (int t = 0; t < 4; ++t) {
        int b = bg * 16 + wv * 4 + t;
        const float4* mrow = (const float4*)(mask + ((size_t)b * NN + row) * NN);
        mA[t] = mrow[2 * lane];
        mB[t] = mrow[2 * lane + 1];
    }
    #pragma unroll
    for (int t = 0; t < 4; ++t) {
        int b = bg * 16 + wv * 4 + t;
        // fp32 products: used for rowsum (exact, same as R5) and bf16 A store
        float p0 = mA[t].x * sA.x, p1 = mA[t].y * sA.y;
        float p2 = mA[t].z * sA.z, p3 = mA[t].w * sA.w;
        float p4 = mB[t].x * sB.x, p5 = mB[t].y * sB.y;
        float p6 = mB[t].z * sB.z, p7 = mB[t].w * sB.w;

        uint4 pk;
        pk.x = bf16u(p0) | (bf16u(p1) << 16);
        pk.y = bf16u(p2) | (bf16u(p3) << 16);
        pk.z = bf16u(p4) | (bf16u(p5) << 16);
        pk.w = bf16u(p6) | (bf16u(p7) << 16);
        *(uint4*)(A + ((size_t)b * NN + row) * NN + lane * 8) = pk;

        float sum = p0 + p1 + p2 + p3 + p4 + p5 + p6 + p7;
        #pragma unroll
        for (int off = 32; off > 0; off >>= 1)
            sum += __shfl_down(sum, off, 64);
        if (lane == 0) {
            float rs = sum + 1.0f;
            dvec[b * NN + row] = (rs > 0.f) ? (1.0f / sqrtf(rs)) : 0.f;
        }
    }
}

// ---- Kernel 2: Xt[b][f][j] = bf16(d_j * x[b][j][f])  (per-batch transpose) -
__global__ __launch_bounds__(256) void xt_kernel(const float* __restrict__ in,
                                                 const float* __restrict__ dvec,
                                                 unsigned short* __restrict__ Xt) {
    __shared__ unsigned short T[64 * PADT];
    const int b = blockIdx.y;
    const int j0 = blockIdx.x * 64;
    const int tid = threadIdx.x;

    const int fg = tid & 31;
    const int jr = tid >> 5;
    #pragma unroll
    for (int p = 0; p < 8; ++p) {
        int j = jr + 8 * p;
        float dj = dvec[b * NN + j0 + j];
        float4 xv = *(const float4*)(in + ((size_t)b * NN + j0 + j) * FF + 4 * fg);
        T[j * PADT + 4 * fg + 0] = (unsigned short)bf16u(xv.x * dj);
        T[j * PADT + 4 * fg + 1] = (unsigned short)bf16u(xv.y * dj);
        T[j * PADT + 4 * fg + 2] = (unsigned short)bf16u(xv.z * dj);
        T[j * PADT + 4 * fg + 3] = (unsigned short)bf16u(xv.w * dj);
    }
    __syncthreads();
    const int c = tid & 7;
    const int fr = tid >> 3;
    #pragma unroll
    for (int q = 0; q < 4; ++q) {
        int f = fr + 32 * q;
        unsigned int v01 = (unsigned int)T[(8 * c + 0) * PADT + f] |
                           ((unsigned int)T[(8 * c + 1) * PADT + f] << 16);
        unsigned int v23 = (unsigned int)T[(8 * c + 2) * PADT + f] |
                           ((unsigned int)T[(8 * c + 3) * PADT + f] << 16);
        unsigned int v45 = (unsigned int)T[(8 * c + 4) * PADT + f] |
                           ((unsigned int)T[(8 * c + 5) * PADT + f] << 16);
        unsigned int v67 = (unsigned int)T[(8 * c + 6) * PADT + f] |
                           ((unsigned int)T[(8 * c + 7) * PADT + f] << 16);
        *(uint4*)(Xt + ((size_t)b * FF + f) * NN + j0 + 8 * c) = make_uint4(v01, v23, v45, v67);
    }
}

// ---- Kernel 3: MFMA matmul, TI=16, A pre-multiplied bf16 from global -------
// R5 structure: A double-buffered in LDS (coalesced uint2 stage/thread),
// B-frags prefetched from L2-resident Xt, one barrier per 64-k chunk.
__global__ __launch_bounds__(256) void matmul_kernel(
        const unsigned short* __restrict__ A, const float* __restrict__ dvec,
        const unsigned short* __restrict__ Xt, const float* __restrict__ in,
        float* __restrict__ out) {
    __shared__ __align__(16) unsigned short Alds[2][TI2 * ASTR];

    const int b = blockIdx.y;
    const int i_base = blockIdx.x * TI2;
    const int tid = threadIdx.x;
    const int wv = tid >> 6;
    const int lane = tid & 63;
    const int quad = lane >> 4;
    const int l16 = lane & 15;
    const int fw = wv * 32;

    const float* dB = dvec + b * NN;
    const unsigned short* XtB = Xt + (size_t)b * FF * NN;

    floatx4 acc[2];
    acc[0] = (floatx4){0.f, 0.f, 0.f, 0.f};
    acc[1] = (floatx4){0.f, 0.f, 0.f, 0.f};

    // A staging: thread t -> row t>>4 (0..15), j-offset (t&15)*4 (uint2 = 8B)
    const int a_il = tid >> 4;
    const int a_js = (tid & 15) * 4;
    const unsigned short* abase = A + ((size_t)b * NN + i_base + a_il) * NN + a_js;

    // prologue: stage chunk 0 into buffer 0
    *(uint2*)(&Alds[0][0] + a_il * ASTR + a_js) = *(const uint2*)abase;

    // prefetch B-frags for chunk 0: [s][nt]
    bf16x8 bcur[4];
    #pragma unroll
    for (int s = 0; s < 2; ++s)
        #pragma unroll
        for (int nt = 0; nt < 2; ++nt)
            bcur[s * 2 + nt] = *(const bf16x8*)&XtB[(size_t)(fw + nt * 16 + l16) * NN + s * 32 + quad * 8];

    #pragma unroll
    for (int c = 0; c < 8; ++c) {
        const int p = c & 1;
        uint2 av;
        if (c < 7) av = *(const uint2*)(abase + (c + 1) * 64);
        __syncthreads();   // Alds[p] writes visible; prior reads of Alds[p^1] done

        bf16x8 bnxt[4];
        if (c < 7) {
            int jn = (c + 1) * 64;
            #pragma unroll
            for (int s = 0; s < 2; ++s)
                #pragma unroll
                for (int nt = 0; nt < 2; ++nt)
                    bnxt[s * 2 + nt] = *(const bf16x8*)&XtB[(size_t)(fw + nt * 16 + l16) * NN + jn + s * 32 + quad * 8];
        }

        #pragma unroll
        for (int s = 0; s < 2; ++s) {
            bf16x8 af = *(const bf16x8*)&Alds[p][l16 * ASTR + s * 32 + quad * 8];
            #pragma unroll
            for (int nt = 0; nt < 2; ++nt)
                acc[nt] = __builtin_amdgcn_mfma_f32_16x16x32_bf16(af, bcur[s * 2 + nt], acc[nt], 0, 0, 0);
        }

        if (c < 7) {
            *(uint2*)(&Alds[p ^ 1][0] + a_il * ASTR + a_js) = av;
            #pragma unroll
            for (int q = 0; q < 4; ++q) bcur[q] = bnxt[q];
        }
    }

    // epilogue: out = d_i * (acc + d_i * x_i), identity term in fp32
    #pragma unroll
    for (int nt = 0; nt < 2; ++nt) {
        int f = fw + nt * 16 + l16;
        #pragma unroll
        for (int r = 0; r < 4; ++r) {
            int i = i_base + quad * 4 + r;
            float di = dB[i];
            float x = in[((size_t)b * NN + i) * FF + f];
            out[((size_t)b * NN + i) * FF + f] = di * (acc[nt][r] + di * x);
        }
    }
}

extern "C" void kernel_launch(void* const* d_in, const int* in_sizes, int n_in,
                              void* d_out, int out_size, void* d_ws, size_t ws_size,
                              hipStream_t stream) {
    const float* inp  = (const float*)d_in[0];   // [B,N,F]
    const float* mask = (const float*)d_in[1];   // [B,N,N]
    const float* w    = (const float*)d_in[2];   // [N,N]
    float* out = (float*)d_out;                  // [B,N,F]

    unsigned short* A  = (unsigned short*)d_ws;              // [B,N,N] bf16 = 33.5 MB
    unsigned short* Xt = A + (size_t)BB * NN * NN;           // [B,F,N] bf16 = 8.4 MB
    float* dvec = (float*)(Xt + (size_t)BB * FF * NN);       // [B,N] f32

    softmax_rowsum_A_kernel<<<dim3(NN, 4), 256, 0, stream>>>(w, mask, A, dvec);
    xt_kernel<<<dim3(NN / 64, BB), 256, 0, stream>>>(inp, dvec, Xt);
    matmul_kernel<<<dim3(NN / TI2, BB), 256, 0, stream>>>(A, dvec, Xt, inp, out);
}